// Round 6
// baseline (426.511 us; speedup 1.0000x reference)
//
#include <hip/hip_runtime.h>

#define NPTS  262144
#define NV    6890
#define NVP   6896          // = 431 * 16, padded
#define NJ    24
#define NGRP  431           // 16 verts per group

typedef float f32x16 __attribute__((ext_vector_type(16)));

// Pack verts as [-2x, -2y, -2z, |v|^2]: d~ = |v|^2 - 2 q.v (argmin-equivalent).
// |v|^2 in numpy's rounding order: (x*x + y*y) + z*z.
__global__ void pack_verts_kernel(const float* __restrict__ verts, float4* __restrict__ vp) {
    int v = blockIdx.x * 256 + threadIdx.x;
    if (v >= NVP) return;
    if (v < NV) {
        float x = verts[3*v+0], y = verts[3*v+1], z = verts[3*v+2];
        float vs = __fadd_rn(__fadd_rn(__fmul_rn(x,x), __fmul_rn(y,y)), __fmul_rn(z,z));
        vp[v] = make_float4(-2.f*x, -2.f*y, -2.f*z, vs);
    } else {
        vp[v] = make_float4(0.f, 0.f, 0.f, 3.0e37f);  // pad: never selected
    }
}

// Wave-uniform vertex stream via the SCALAR pipe: 4 verts per s_load_dwordx16.
__device__ __forceinline__ f32x16 sload16(const float* p, uint32_t byte_off) {
    f32x16 r;
    asm volatile("s_load_dwordx16 %0, %1, %2"
                 : "=&s"(r) : "s"(p), "s"(byte_off));
    return r;
}

__device__ __forceinline__ void swait() {
    asm volatile("s_waitcnt lgkmcnt(0)" ::: "memory");
    __builtin_amdgcn_sched_barrier(0);   // rule #18: keep consumers below the wait
}

template<int PACKED>
__global__ __launch_bounds__(256)
void knn_blend_kernel(const float* __restrict__ qpts,
                      const float* __restrict__ pp,
                      const float* __restrict__ verts,
                      const float* __restrict__ weights,
                      const float* __restrict__ At,
                      const float* __restrict__ Ab,
                      float* __restrict__ out)
{
    __shared__ float sAt[NJ*16];
    __shared__ float sAb[NJ*16];
    const int tid = threadIdx.x;
    for (int i = tid; i < NJ*16; i += 256) { sAt[i] = At[i]; sAb[i] = Ab[i]; }

    const int n = blockIdx.x * 256 + tid;
    const float q0 = qpts[3*n+0], q1 = qpts[3*n+1], q2 = qpts[3*n+2];

    int bi = 0;

    if (PACKED) {
        // even/odd split accumulators break the serial cmp->cndmask chain
        float bE = 3.4e38f, bO = 3.4e38f;
        int   iE = 0,       iO = 1;
        uint32_t off = 0;
        for (int g = 0; g < NGRP; ++g) {
            f32x16 w0 = sload16(pp, off);
            f32x16 w1 = sload16(pp, off + 64u);
            f32x16 w2 = sload16(pp, off + 128u);
            f32x16 w3 = sload16(pp, off + 192u);
            swait();
            const int vb = g * 16;
#pragma unroll
            for (int k = 0; k < 4; ++k) {
                const f32x16 w = (k==0)?w0:(k==1)?w1:(k==2)?w2:w3;
#pragma unroll
                for (int j = 0; j < 4; ++j) {
                    // each VALU op reads at most ONE SGPR operand
                    float d = __fmul_rn(q0, w[4*j+0]);
                    d = fmaf(q1, w[4*j+1], d);
                    d = fmaf(q2, w[4*j+2], d);
                    d = __fadd_rn(d, w[4*j+3]);
                    const int cand = vb + k*4 + j;   // uniform -> SGPR
                    if (((k*4 + j) & 1) == 0) {
                        bool lt = d < bE;  bE = lt ? d : bE;  iE = lt ? cand : iE;
                    } else {
                        bool lt = d < bO;  bO = lt ? d : bO;  iO = lt ? cand : iO;
                    }
                }
            }
            off += 256u;
        }
        // merge; exact tie -> smaller index (numpy first-occurrence)
        if (bO < bE)      bi = iO;
        else if (bE < bO) bi = iE;
        else              bi = (iE < iO) ? iE : iO;
    } else {
        // fallback (no workspace): direct scan, reference-shaped rounding
        const float qsq = __fadd_rn(__fadd_rn(__fmul_rn(q0,q0), __fmul_rn(q1,q1)), __fmul_rn(q2,q2));
        float best = 3.4e38f;
        for (int v = 0; v < NV; ++v) {
            float vx = verts[3*v+0], vy = verts[3*v+1], vz = verts[3*v+2];
            float vs = __fadd_rn(__fadd_rn(__fmul_rn(vx,vx), __fmul_rn(vy,vy)), __fmul_rn(vz,vz));
            float tq = fmaf(q2, vz, fmaf(q1, vy, __fmul_rn(q0, vx)));
            float d  = __fadd_rn(__fsub_rn(qsq, __fadd_rn(tq, tq)), vs);
            bool lt = d < best;
            best = lt ? d : best;
            bi   = lt ? v : bi;
        }
    }

    __syncthreads();   // sAt/sAb staged

    // Blend the two transform stacks with the gathered weight row (rows 0..2 only).
    const float* wrow = weights + bi * NJ;
    float M1[12], M2[12];
#pragma unroll
    for (int i = 0; i < 12; ++i) { M1[i] = 0.f; M2[i] = 0.f; }
    for (int k = 0; k < NJ; ++k) {
        const float w = wrow[k];
        const float* a = sAt + k*16;
        const float* b = sAb + k*16;
#pragma unroll
        for (int i = 0; i < 12; ++i) {
            M1[i] = fmaf(w, a[i], M1[i]);
            M2[i] = fmaf(w, b[i], M2[i]);
        }
    }

    // can = inv(M1[:3,:3]) @ (q - M1[:,3])  via adjugate/det (well-conditioned)
    float p0 = q0 - M1[3], p1 = q1 - M1[7], p2 = q2 - M1[11];
    float a_=M1[0], b_=M1[1], c_=M1[2];
    float d_=M1[4], e_=M1[5], f_=M1[6];
    float g_=M1[8], h_=M1[9], i_=M1[10];
    float A0 = e_*i_ - f_*h_, A1 = c_*h_ - b_*i_, A2 = b_*f_ - c_*e_;
    float A3 = f_*g_ - d_*i_, A4 = a_*i_ - c_*g_, A5 = c_*d_ - a_*f_;
    float A6 = d_*h_ - e_*g_, A7 = b_*g_ - a_*h_, A8 = a_*e_ - b_*d_;
    float det  = a_*A0 + b_*A3 + c_*A6;
    float rdet = 1.0f / det;
    float x0 = (A0*p0 + A1*p1 + A2*p2) * rdet;
    float x1 = (A3*p0 + A4*p1 + A5*p2) * rdet;
    float x2 = (A6*p0 + A7*p1 + A8*p2) * rdet;

    // out = M2[:3,:3] @ can + M2[:,3]
    float o0 = fmaf(M2[0],x0, fmaf(M2[1],x1, fmaf(M2[2], x2, M2[3])));
    float o1 = fmaf(M2[4],x0, fmaf(M2[5],x1, fmaf(M2[6], x2, M2[7])));
    float o2 = fmaf(M2[8],x0, fmaf(M2[9],x1, fmaf(M2[10],x2, M2[11])));

    out[3*n+0] = o0; out[3*n+1] = o1; out[3*n+2] = o2;
}

extern "C" void kernel_launch(void* const* d_in, const int* in_sizes, int n_in,
                              void* d_out, int out_size, void* d_ws, size_t ws_size,
                              hipStream_t stream) {
    const float* qpts    = (const float*)d_in[0];
    const float* verts   = (const float*)d_in[1];
    const float* weights = (const float*)d_in[2];
    const float* At      = (const float*)d_in[3];
    const float* Ab      = (const float*)d_in[4];
    float* out = (float*)d_out;

    const size_t need = (size_t)NVP * sizeof(float4);
    if (ws_size >= need) {
        float* pp = (float*)d_ws;
        pack_verts_kernel<<<(NVP + 255) / 256, 256, 0, stream>>>(verts, (float4*)pp);
        knn_blend_kernel<1><<<NPTS / 256, 256, 0, stream>>>(qpts, pp, verts, weights, At, Ab, out);
    } else {
        knn_blend_kernel<0><<<NPTS / 256, 256, 0, stream>>>(qpts, nullptr, verts, weights, At, Ab, out);
    }
}